// Round 5
// baseline (613.188 us; speedup 1.0000x reference)
//
#include <hip/hip_runtime.h>

#define NPTS 400000
#define KOFF 27

typedef __attribute__((ext_vector_type(8))) __bf16 bf16x8;
typedef __attribute__((ext_vector_type(4))) float v4f;

__device__ __forceinline__ float bf2f(unsigned short u) {
  union { unsigned int i; float f; } v; v.i = ((unsigned int)u) << 16; return v.f;
}
__device__ __forceinline__ unsigned short f2bf(float f) {
  union { float f; unsigned int i; } v; v.f = f;
  unsigned int x = v.i;
  return (unsigned short)((x + 0x7FFFu + ((x >> 16) & 1u)) >> 16);  // RNE
}

// ---------------------------------------------------------------- fused prep:
//  all blocks: feats -> bf16 table;  block 0: sentinels + stats zero
//  blocks <1563: nbr/mask -> masked transposed nbrT (LDS tile)
//  blocks 1563..1670: W -> fragment-major bf16
__global__ void prep_all(const float* __restrict__ feats, unsigned short* __restrict__ Xb,
                         unsigned short* __restrict__ H1, float* __restrict__ statszero,
                         const int* __restrict__ nbr, const int* __restrict__ mask,
                         int* __restrict__ nbrT,
                         const float* __restrict__ W1, const float* __restrict__ W2,
                         unsigned short* __restrict__ WL1, unsigned short* __restrict__ WL2) {
  __shared__ int tile[256 * KOFF];
  int idx = blockIdx.x * 256 + threadIdx.x;          // 6250*256 = 1.6M = NPTS*32/8
  const float4* f4 = (const float4*)feats;
  float4 a = f4[2 * idx], b = f4[2 * idx + 1];
  union { unsigned short u[8]; uint4 v; } p;
  p.u[0] = f2bf(a.x); p.u[1] = f2bf(a.y); p.u[2] = f2bf(a.z); p.u[3] = f2bf(a.w);
  p.u[4] = f2bf(b.x); p.u[5] = f2bf(b.y); p.u[6] = f2bf(b.z); p.u[7] = f2bf(b.w);
  ((uint4*)Xb)[idx] = p.v;
  if (blockIdx.x == 0) {
    if (threadIdx.x < 32) {                           // zero sentinel row NPTS in both gatherable tables
      Xb[(size_t)NPTS * 32 + threadIdx.x] = 0;
      H1[(size_t)NPTS * 32 + threadIdx.x] = 0;
    }
    if (threadIdx.x < 128) statszero[threadIdx.x] = 0.f;  // stats1[64] + stats2[64] contiguous
  }
  if (blockIdx.x < 1563) {                            // nbr tile transpose
    int p0 = blockIdx.x * 256;
    int cnt = (NPTS - p0 < 256) ? (NPTS - p0) : 256;
    int total = cnt * KOFF;
    for (int i = threadIdx.x; i < total; i += 256) {
      int j = nbr[(size_t)p0 * KOFF + i];
      int mk = mask[(size_t)p0 * KOFF + i];
      tile[i] = (mk != 0) ? j : NPTS;                 // sentinel -> zero row
    }
    __syncthreads();
    int t = threadIdx.x;
    if (t < cnt) {
      #pragma unroll
      for (int k = 0; k < KOFF; ++k)
        nbrT[(size_t)k * NPTS + p0 + t] = tile[t * KOFF + k];
    }
  } else if (blockIdx.x < 1563 + 108) {               // W -> fragment-major
    int widx = (blockIdx.x - 1563) * 256 + threadIdx.x;
    if (widx < KOFF * 1024) {
      int k = widx >> 10, r = widx & 1023;
      int h = r >> 9, rr = r & 511;
      int lane = rr >> 3, j = rr & 7;
      int i_ch = (lane >> 4) * 8 + j;
      int o_ch = h * 16 + (lane & 15);
      int src = k * 1024 + i_ch * 32 + o_ch;
      WL1[widx] = f2bf(W1[src]);
      WL2[widx] = f2bf(W2[src]);
    }
  }
}

// ---------------------------------------------------------------- sparse conv, 16x16x32 MFMA, pinned gather pipeline
// wave = 16 points x 32 outputs; 8 waves/block; 18 gathers in flight at the
// staging barrier (its vmcnt(0) drain IS the latency-hiding point), 9 more mid-kernel
__global__ __launch_bounds__(512, 4) void conv_mfma16(
    const unsigned short* __restrict__ X,     // (NPTS+1) x 32 bf16, row NPTS = zeros
    const int* __restrict__ nbrT,             // [27][NPTS]
    const unsigned short* __restrict__ WL,    // fragment-major [27][2][64][8] bf16
    unsigned short* __restrict__ Hout,        // [NPTS][32] bf16
    float* __restrict__ stats)                // [64]: sum, sumsq
{
  __shared__ unsigned char wlds[KOFF * 2048]; // 54 KB: [k][h][lane][16B]
  __shared__ float redS[8][32];
  __shared__ float redQ[8][32];

  const int tid  = threadIdx.x;
  const int lane = tid & 63;
  const int wv   = tid >> 6;            // 0..7
  const int m    = lane & 15;           // point-in-tile / out-ch
  const int q    = lane >> 4;           // input-channel chunk
  const int n0   = blockIdx.x * 128 + wv * 16;   // 3125*128 = 400000 exactly

  // (1) W staging loads (independent)
  uint4 wtmp[7];
  {
    const uint4* wsrc = (const uint4*)WL;
    #pragma unroll
    for (int i = 0; i < 7; ++i) {
      int ii = i * 512 + tid;
      if (ii < KOFF * 128) wtmp[i] = wsrc[ii];
    }
  }
  // (2) neighbor index loads (overlap W latency)
  const int* nbp = nbrT + n0 + m;
  int nb[KOFF];
  #pragma unroll
  for (int k = 0; k < KOFF; ++k) nb[k] = nbp[k * NPTS];

  // (3) write W to LDS (waits only the wtmp loads, nb stays in flight)
  {
    uint4* dst = (uint4*)wlds;
    #pragma unroll
    for (int i = 0; i < 7; ++i) {
      int ii = i * 512 + tid;
      if (ii < KOFF * 128) dst[ii] = wtmp[i];
    }
  }

  // (4) issue 18 A-gathers; sched_barrier pins them before the block barrier
  const unsigned short* xq = X + q * 8;
  bf16x8 A0[9], A1[9];
  #pragma unroll
  for (int k = 0; k < 9; ++k) A0[k] = *(const bf16x8*)(xq + (size_t)nb[k] * 32);
  #pragma unroll
  for (int k = 0; k < 9; ++k) A1[k] = *(const bf16x8*)(xq + (size_t)nb[9 + k] * 32);
  __builtin_amdgcn_sched_barrier(0);

  // (5) barrier: vmcnt(0) drain happens with 18 gathers/wave in flight, all waves at once
  __syncthreads();

  const bf16x8* wfrag = (const bf16x8*)wlds;
  v4f acc0 = {0.f, 0.f, 0.f, 0.f};
  v4f acc1 = {0.f, 0.f, 0.f, 0.f};

  // (6) chunk 0 compute: pure LDS+MFMA
  #pragma unroll
  for (int k = 0; k < 9; ++k) {
    bf16x8 b0 = wfrag[(k * 2 + 0) * 64 + lane];
    bf16x8 b1 = wfrag[(k * 2 + 1) * 64 + lane];
    acc0 = __builtin_amdgcn_mfma_f32_16x16x32_bf16(A0[k], b0, acc0, 0, 0, 0);
    acc1 = __builtin_amdgcn_mfma_f32_16x16x32_bf16(A0[k], b1, acc1, 0, 0, 0);
  }
  __builtin_amdgcn_sched_barrier(0);
  // (7) chunk 2 gathers issue here, overlapping chunk 1 compute
  #pragma unroll
  for (int k = 0; k < 9; ++k) A0[k] = *(const bf16x8*)(xq + (size_t)nb[18 + k] * 32);
  __builtin_amdgcn_sched_barrier(0);
  #pragma unroll
  for (int k = 0; k < 9; ++k) {        // chunk 1 compute
    int kk = 9 + k;
    bf16x8 b0 = wfrag[(kk * 2 + 0) * 64 + lane];
    bf16x8 b1 = wfrag[(kk * 2 + 1) * 64 + lane];
    acc0 = __builtin_amdgcn_mfma_f32_16x16x32_bf16(A1[k], b0, acc0, 0, 0, 0);
    acc1 = __builtin_amdgcn_mfma_f32_16x16x32_bf16(A1[k], b1, acc1, 0, 0, 0);
  }
  #pragma unroll
  for (int k = 0; k < 9; ++k) {        // chunk 2 compute
    int kk = 18 + k;
    bf16x8 b0 = wfrag[(kk * 2 + 0) * 64 + lane];
    bf16x8 b1 = wfrag[(kk * 2 + 1) * 64 + lane];
    acc0 = __builtin_amdgcn_mfma_f32_16x16x32_bf16(A0[k], b0, acc0, 0, 0, 0);
    acc1 = __builtin_amdgcn_mfma_f32_16x16x32_bf16(A0[k], b1, acc1, 0, 0, 0);
  }

  // epilogue: C/D layout col=lane&15 (=out ch m), row=(lane>>4)*4+r (=point)
  float s0 = 0.f, s1 = 0.f, qq0 = 0.f, qq1 = 0.f;
  #pragma unroll
  for (int r = 0; r < 4; ++r) {
    float v0 = acc0[r], v1 = acc1[r];
    s0 += v0; s1 += v1; qq0 += v0 * v0; qq1 += v1 * v1;
    size_t pt = (size_t)(n0 + q * 4 + r);
    Hout[pt * 32 + m]      = f2bf(v0);
    Hout[pt * 32 + 16 + m] = f2bf(v1);
  }
  // BN stats: reduce over point-chunk lanes (bits 4,5)
  s0  += __shfl_xor(s0, 16);  s0  += __shfl_xor(s0, 32);
  s1  += __shfl_xor(s1, 16);  s1  += __shfl_xor(s1, 32);
  qq0 += __shfl_xor(qq0, 16); qq0 += __shfl_xor(qq0, 32);
  qq1 += __shfl_xor(qq1, 16); qq1 += __shfl_xor(qq1, 32);
  if (lane < 16) {
    redS[wv][m] = s0; redS[wv][m + 16] = s1;
    redQ[wv][m] = qq0; redQ[wv][m + 16] = qq1;
  }
  __syncthreads();
  if (tid < 64) {
    int t = tid & 31;
    float a = 0.f;
    if (tid < 32) { for (int w = 0; w < 8; ++w) a += redS[w][t]; }
    else          { for (int w = 0; w < 8; ++w) a += redQ[w][t]; }
    atomicAdd(&stats[tid], a);
  }
}

// ---------------------------------------------------------------- BN(+finalize) + ReLU in place (bf16)
__global__ void bn_relu_fused(unsigned short* __restrict__ H, const float* __restrict__ stats,
                              const float* __restrict__ gamma, const float* __restrict__ beta) {
  __shared__ float sb[64];
  if (threadIdx.x < 32) {
    int t = threadIdx.x;
    float mean = stats[t] * (1.f / NPTS);
    float var  = stats[t + 32] * (1.f / NPTS) - mean * mean;
    float rstd = rsqrtf(var + 1e-5f);
    float sc = gamma[t] * rstd;
    sb[t] = sc; sb[t + 32] = beta[t] - mean * sc;
  }
  __syncthreads();
  int idx = blockIdx.x * 256 + threadIdx.x;          // 1.6M
  uint4 v = ((uint4*)H)[idx];
  union { uint4 v; unsigned short u[8]; } p; p.v = v;
  int baseo = (idx * 8) & 31;
  #pragma unroll
  for (int j = 0; j < 8; ++j) {
    float f = bf2f(p.u[j]);
    f = fmaxf(f * sb[baseo + j] + sb[32 + baseo + j], 0.f);
    p.u[j] = f2bf(f);
  }
  ((uint4*)H)[idx] = p.v;
}

// ---------------------------------------------------------------- BN(+finalize) + residual + ReLU -> fp32 out
__global__ void bn_res_relu_out(const unsigned short* __restrict__ H2, const float* __restrict__ feats,
                                const float* __restrict__ stats, const float* __restrict__ gamma,
                                const float* __restrict__ beta, float* __restrict__ out) {
  __shared__ float sb[64];
  if (threadIdx.x < 32) {
    int t = threadIdx.x;
    float mean = stats[t] * (1.f / NPTS);
    float var  = stats[t + 32] * (1.f / NPTS) - mean * mean;
    float rstd = rsqrtf(var + 1e-5f);
    float sc = gamma[t] * rstd;
    sb[t] = sc; sb[t + 32] = beta[t] - mean * sc;
  }
  __syncthreads();
  int idx = blockIdx.x * 256 + threadIdx.x;          // 1.6M
  uint4 v = ((const uint4*)H2)[idx];
  union { uint4 v; unsigned short u[8]; } p; p.v = v;
  int baseo = (idx * 8) & 31;
  const float4* f4 = (const float4*)feats;
  float4 fa = f4[2 * idx], fb = f4[2 * idx + 1];
  float4 o0, o1;
  float* fav = (float*)&fa; float* fbv = (float*)&fb;
  float* o0v = (float*)&o0; float* o1v = (float*)&o1;
  #pragma unroll
  for (int j = 0; j < 4; ++j)
    o0v[j] = fmaxf(bf2f(p.u[j]) * sb[baseo + j] + sb[32 + baseo + j] + fav[j], 0.f);
  #pragma unroll
  for (int j = 0; j < 4; ++j)
    o1v[j] = fmaxf(bf2f(p.u[4 + j]) * sb[baseo + 4 + j] + sb[32 + baseo + 4 + j] + fbv[j], 0.f);
  ((float4*)out)[2 * idx] = o0;
  ((float4*)out)[2 * idx + 1] = o1;
}

// ----------------------------------------------------------------
extern "C" void kernel_launch(void* const* d_in, const int* in_sizes, int n_in,
                              void* d_out, int out_size, void* d_ws, size_t ws_size,
                              hipStream_t stream) {
  const float* feats  = (const float*)d_in[0];
  const float* W1     = (const float*)d_in[1];
  const float* gamma1 = (const float*)d_in[2];
  const float* beta1  = (const float*)d_in[3];
  const float* W2     = (const float*)d_in[4];
  const float* gamma2 = (const float*)d_in[5];
  const float* beta2  = (const float*)d_in[6];
  const int*   nbr    = (const int*)d_in[7];
  const int*   mask   = (const int*)d_in[8];   // jnp bool uploaded as int32

  char* ws = (char*)d_ws;
  const size_t XB = ((size_t)(NPTS + 1) * 32 * 2 + 255) & ~(size_t)255;
  unsigned short* Xb   = (unsigned short*)(ws);
  unsigned short* H1   = (unsigned short*)(ws + XB);
  int*            nbrT = (int*)(ws + 2 * XB);
  size_t off = 2 * XB + (size_t)KOFF * NPTS * 4;
  unsigned short* WL1 = (unsigned short*)(ws + off); off += KOFF * 1024 * 2;
  unsigned short* WL2 = (unsigned short*)(ws + off); off += KOFF * 1024 * 2;
  float* stats1 = (float*)(ws + off); off += 256;
  float* stats2 = (float*)(ws + off); off += 256;
  unsigned short* H2 = Xb;   // overlay: Xb dead after conv1

  prep_all<<<6250, 256, 0, stream>>>(feats, Xb, H1, stats1, nbr, mask, nbrT, W1, W2, WL1, WL2);

  conv_mfma16<<<3125, 512, 0, stream>>>(Xb, nbrT, WL1, H1, stats1);
  bn_relu_fused<<<6250, 256, 0, stream>>>(H1, stats1, gamma1, beta1);

  conv_mfma16<<<3125, 512, 0, stream>>>(H1, nbrT, WL2, H2, stats2);
  bn_res_relu_out<<<6250, 256, 0, stream>>>(H2, feats, stats2, gamma2, beta2, (float*)d_out);
}

// Round 6
// 599.521 us; speedup vs baseline: 1.0228x; 1.0228x over previous
//
#include <hip/hip_runtime.h>

#define NPTS 400000
#define KOFF 27

typedef __attribute__((ext_vector_type(8))) __bf16 bf16x8;
typedef __attribute__((ext_vector_type(4))) float v4f;

__device__ __forceinline__ float bf2f(unsigned short u) {
  union { unsigned int i; float f; } v; v.i = ((unsigned int)u) << 16; return v.f;
}
__device__ __forceinline__ unsigned short f2bf(float f) {
  union { float f; unsigned int i; } v; v.f = f;
  unsigned int x = v.i;
  return (unsigned short)((x + 0x7FFFu + ((x >> 16) & 1u)) >> 16);  // RNE
}

// ---------------------------------------------------------------- fused prep:
//  all blocks: feats -> bf16 table;  block 0: sentinels + stats zero
//  blocks <1563: nbr/mask -> masked transposed nbrT (LDS tile)
//  blocks 1563..1670: W -> fragment-major bf16
__global__ void prep_all(const float* __restrict__ feats, unsigned short* __restrict__ Xb,
                         unsigned short* __restrict__ H1, float* __restrict__ statszero,
                         const int* __restrict__ nbr, const int* __restrict__ mask,
                         int* __restrict__ nbrT,
                         const float* __restrict__ W1, const float* __restrict__ W2,
                         unsigned short* __restrict__ WL1, unsigned short* __restrict__ WL2) {
  __shared__ int tile[256 * KOFF];
  int idx = blockIdx.x * 256 + threadIdx.x;          // 6250*256 = 1.6M = NPTS*32/8
  const float4* f4 = (const float4*)feats;
  float4 a = f4[2 * idx], b = f4[2 * idx + 1];
  union { unsigned short u[8]; uint4 v; } p;
  p.u[0] = f2bf(a.x); p.u[1] = f2bf(a.y); p.u[2] = f2bf(a.z); p.u[3] = f2bf(a.w);
  p.u[4] = f2bf(b.x); p.u[5] = f2bf(b.y); p.u[6] = f2bf(b.z); p.u[7] = f2bf(b.w);
  ((uint4*)Xb)[idx] = p.v;
  if (blockIdx.x == 0) {
    if (threadIdx.x < 32) {                           // zero sentinel row NPTS in both gatherable tables
      Xb[(size_t)NPTS * 32 + threadIdx.x] = 0;
      H1[(size_t)NPTS * 32 + threadIdx.x] = 0;
    }
    if (threadIdx.x < 128) statszero[threadIdx.x] = 0.f;  // stats1[64] + stats2[64] contiguous
  }
  if (blockIdx.x < 1563) {                            // nbr tile transpose
    int p0 = blockIdx.x * 256;
    int cnt = (NPTS - p0 < 256) ? (NPTS - p0) : 256;
    int total = cnt * KOFF;
    for (int i = threadIdx.x; i < total; i += 256) {
      int j = nbr[(size_t)p0 * KOFF + i];
      int mk = mask[(size_t)p0 * KOFF + i];
      tile[i] = (mk != 0) ? j : NPTS;                 // sentinel -> zero row
    }
    __syncthreads();
    int t = threadIdx.x;
    if (t < cnt) {
      #pragma unroll
      for (int k = 0; k < KOFF; ++k)
        nbrT[(size_t)k * NPTS + p0 + t] = tile[t * KOFF + k];
    }
  } else if (blockIdx.x < 1563 + 108) {               // W -> fragment-major
    int widx = (blockIdx.x - 1563) * 256 + threadIdx.x;
    if (widx < KOFF * 1024) {
      int k = widx >> 10, r = widx & 1023;
      int h = r >> 9, rr = r & 511;
      int lane = rr >> 3, j = rr & 7;
      int i_ch = (lane >> 4) * 8 + j;
      int o_ch = h * 16 + (lane & 15);
      int src = k * 1024 + i_ch * 32 + o_ch;
      WL1[widx] = f2bf(W1[src]);
      WL2[widx] = f2bf(W2[src]);
    }
  }
}

// ---------------------------------------------------------------- sparse conv, 16x16x32 MFMA, pinned gather pipeline
// Spill-proof phase order: nbr loads -> W loads -> W ds_write (wtmp dies)
// -> 18 A-gathers -> barrier (vmcnt(0) drain with ~288 lines in flight/CU)
__global__ __launch_bounds__(512, 4) void conv_mfma16(
    const unsigned short* __restrict__ X,     // (NPTS+1) x 32 bf16, row NPTS = zeros
    const int* __restrict__ nbrT,             // [27][NPTS]
    const unsigned short* __restrict__ WL,    // fragment-major [27][2][64][8] bf16
    unsigned short* __restrict__ Hout,        // [NPTS][32] bf16
    float* __restrict__ stats)                // [64]: sum, sumsq
{
  __shared__ unsigned char wlds[KOFF * 2048]; // 54 KB: [k][h][lane][16B]
  __shared__ float redS[8][32];
  __shared__ float redQ[8][32];

  const int tid  = threadIdx.x;
  const int lane = tid & 63;
  const int wv   = tid >> 6;            // 0..7
  const int m    = lane & 15;           // point-in-tile / out-ch
  const int q    = lane >> 4;           // input-channel chunk
  const int n0   = blockIdx.x * 128 + wv * 16;   // 3125*128 = 400000 exactly

  // (1) neighbor index loads first (27 independent coalesced streams)
  const int* nbp = nbrT + n0 + m;
  int nb[KOFF];
  #pragma unroll
  for (int k = 0; k < KOFF; ++k) nb[k] = nbp[k * NPTS];

  // (2) W staging loads
  uint4 wtmp[7];
  {
    const uint4* wsrc = (const uint4*)WL;
    #pragma unroll
    for (int i = 0; i < 7; ++i) {
      int ii = i * 512 + tid;
      if (ii < KOFF * 128) wtmp[i] = wsrc[ii];
    }
  }
  // (3) write W to LDS; the vmcnt wait here also lands nb[]. wtmp dies here.
  {
    uint4* dst = (uint4*)wlds;
    #pragma unroll
    for (int i = 0; i < 7; ++i) {
      int ii = i * 512 + tid;
      if (ii < KOFF * 128) dst[ii] = wtmp[i];
    }
  }
  __builtin_amdgcn_sched_barrier(0);   // wtmp live range ends before A-frags begin

  // (4) issue 18 A-gathers (peak live ~95 VGPR: A 72 + tail nb 9 + addrs)
  const unsigned short* xq = X + q * 8;
  bf16x8 A0[9], A1[9];
  #pragma unroll
  for (int k = 0; k < 9; ++k) A0[k] = *(const bf16x8*)(xq + (size_t)nb[k] * 32);
  #pragma unroll
  for (int k = 0; k < 9; ++k) A1[k] = *(const bf16x8*)(xq + (size_t)nb[9 + k] * 32);
  __builtin_amdgcn_sched_barrier(0);

  // (5) barrier: vmcnt(0) drain happens with 18 gathers/wave in flight, all waves at once
  __syncthreads();

  const bf16x8* wfrag = (const bf16x8*)wlds;
  v4f acc0 = {0.f, 0.f, 0.f, 0.f};
  v4f acc1 = {0.f, 0.f, 0.f, 0.f};

  // (6) chunk 0 compute: pure LDS+MFMA
  #pragma unroll
  for (int k = 0; k < 9; ++k) {
    bf16x8 b0 = wfrag[(k * 2 + 0) * 64 + lane];
    bf16x8 b1 = wfrag[(k * 2 + 1) * 64 + lane];
    acc0 = __builtin_amdgcn_mfma_f32_16x16x32_bf16(A0[k], b0, acc0, 0, 0, 0);
    acc1 = __builtin_amdgcn_mfma_f32_16x16x32_bf16(A0[k], b1, acc1, 0, 0, 0);
  }
  __builtin_amdgcn_sched_barrier(0);
  // (7) chunk 2 gathers issue here, overlapping chunk 1 compute
  #pragma unroll
  for (int k = 0; k < 9; ++k) A0[k] = *(const bf16x8*)(xq + (size_t)nb[18 + k] * 32);
  __builtin_amdgcn_sched_barrier(0);
  #pragma unroll
  for (int k = 0; k < 9; ++k) {        // chunk 1 compute
    int kk = 9 + k;
    bf16x8 b0 = wfrag[(kk * 2 + 0) * 64 + lane];
    bf16x8 b1 = wfrag[(kk * 2 + 1) * 64 + lane];
    acc0 = __builtin_amdgcn_mfma_f32_16x16x32_bf16(A1[k], b0, acc0, 0, 0, 0);
    acc1 = __builtin_amdgcn_mfma_f32_16x16x32_bf16(A1[k], b1, acc1, 0, 0, 0);
  }
  #pragma unroll
  for (int k = 0; k < 9; ++k) {        // chunk 2 compute
    int kk = 18 + k;
    bf16x8 b0 = wfrag[(kk * 2 + 0) * 64 + lane];
    bf16x8 b1 = wfrag[(kk * 2 + 1) * 64 + lane];
    acc0 = __builtin_amdgcn_mfma_f32_16x16x32_bf16(A0[k], b0, acc0, 0, 0, 0);
    acc1 = __builtin_amdgcn_mfma_f32_16x16x32_bf16(A0[k], b1, acc1, 0, 0, 0);
  }

  // epilogue: C/D layout col=lane&15 (=out ch m), row=(lane>>4)*4+r (=point)
  float s0 = 0.f, s1 = 0.f, qq0 = 0.f, qq1 = 0.f;
  #pragma unroll
  for (int r = 0; r < 4; ++r) {
    float v0 = acc0[r], v1 = acc1[r];
    s0 += v0; s1 += v1; qq0 += v0 * v0; qq1 += v1 * v1;
    size_t pt = (size_t)(n0 + q * 4 + r);
    Hout[pt * 32 + m]      = f2bf(v0);
    Hout[pt * 32 + 16 + m] = f2bf(v1);
  }
  // BN stats: reduce over point-chunk lanes (bits 4,5)
  s0  += __shfl_xor(s0, 16);  s0  += __shfl_xor(s0, 32);
  s1  += __shfl_xor(s1, 16);  s1  += __shfl_xor(s1, 32);
  qq0 += __shfl_xor(qq0, 16); qq0 += __shfl_xor(qq0, 32);
  qq1 += __shfl_xor(qq1, 16); qq1 += __shfl_xor(qq1, 32);
  if (lane < 16) {
    redS[wv][m] = s0; redS[wv][m + 16] = s1;
    redQ[wv][m] = qq0; redQ[wv][m + 16] = qq1;
  }
  __syncthreads();
  if (tid < 64) {
    int t = tid & 31;
    float a = 0.f;
    if (tid < 32) { for (int w = 0; w < 8; ++w) a += redS[w][t]; }
    else          { for (int w = 0; w < 8; ++w) a += redQ[w][t]; }
    atomicAdd(&stats[tid], a);
  }
}

// ---------------------------------------------------------------- BN(+finalize) + ReLU in place (bf16)
__global__ void bn_relu_fused(unsigned short* __restrict__ H, const float* __restrict__ stats,
                              const float* __restrict__ gamma, const float* __restrict__ beta) {
  __shared__ float sb[64];
  if (threadIdx.x < 32) {
    int t = threadIdx.x;
    float mean = stats[t] * (1.f / NPTS);
    float var  = stats[t + 32] * (1.f / NPTS) - mean * mean;
    float rstd = rsqrtf(var + 1e-5f);
    float sc = gamma[t] * rstd;
    sb[t] = sc; sb[t + 32] = beta[t] - mean * sc;
  }
  __syncthreads();
  int idx = blockIdx.x * 256 + threadIdx.x;          // 1.6M
  uint4 v = ((uint4*)H)[idx];
  union { uint4 v; unsigned short u[8]; } p; p.v = v;
  int baseo = (idx * 8) & 31;
  #pragma unroll
  for (int j = 0; j < 8; ++j) {
    float f = bf2f(p.u[j]);
    f = fmaxf(f * sb[baseo + j] + sb[32 + baseo + j], 0.f);
    p.u[j] = f2bf(f);
  }
  ((uint4*)H)[idx] = p.v;
}

// ---------------------------------------------------------------- BN(+finalize) + residual + ReLU -> fp32 out
__global__ void bn_res_relu_out(const unsigned short* __restrict__ H2, const float* __restrict__ feats,
                                const float* __restrict__ stats, const float* __restrict__ gamma,
                                const float* __restrict__ beta, float* __restrict__ out) {
  __shared__ float sb[64];
  if (threadIdx.x < 32) {
    int t = threadIdx.x;
    float mean = stats[t] * (1.f / NPTS);
    float var  = stats[t + 32] * (1.f / NPTS) - mean * mean;
    float rstd = rsqrtf(var + 1e-5f);
    float sc = gamma[t] * rstd;
    sb[t] = sc; sb[t + 32] = beta[t] - mean * sc;
  }
  __syncthreads();
  int idx = blockIdx.x * 256 + threadIdx.x;          // 1.6M
  uint4 v = ((const uint4*)H2)[idx];
  union { uint4 v; unsigned short u[8]; } p; p.v = v;
  int baseo = (idx * 8) & 31;
  const float4* f4 = (const float4*)feats;
  float4 fa = f4[2 * idx], fb = f4[2 * idx + 1];
  float4 o0, o1;
  float* fav = (float*)&fa; float* fbv = (float*)&fb;
  float* o0v = (float*)&o0; float* o1v = (float*)&o1;
  #pragma unroll
  for (int j = 0; j < 4; ++j)
    o0v[j] = fmaxf(bf2f(p.u[j]) * sb[baseo + j] + sb[32 + baseo + j] + fav[j], 0.f);
  #pragma unroll
  for (int j = 0; j < 4; ++j)
    o1v[j] = fmaxf(bf2f(p.u[4 + j]) * sb[baseo + 4 + j] + sb[32 + baseo + 4 + j] + fbv[j], 0.f);
  ((float4*)out)[2 * idx] = o0;
  ((float4*)out)[2 * idx + 1] = o1;
}

// ----------------------------------------------------------------
extern "C" void kernel_launch(void* const* d_in, const int* in_sizes, int n_in,
                              void* d_out, int out_size, void* d_ws, size_t ws_size,
                              hipStream_t stream) {
  const float* feats  = (const float*)d_in[0];
  const float* W1     = (const float*)d_in[1];
  const float* gamma1 = (const float*)d_in[2];
  const float* beta1  = (const float*)d_in[3];
  const float* W2     = (const float*)d_in[4];
  const float* gamma2 = (const float*)d_in[5];
  const float* beta2  = (const float*)d_in[6];
  const int*   nbr    = (const int*)d_in[7];
  const int*   mask   = (const int*)d_in[8];   // jnp bool uploaded as int32

  char* ws = (char*)d_ws;
  const size_t XB = ((size_t)(NPTS + 1) * 32 * 2 + 255) & ~(size_t)255;
  unsigned short* Xb   = (unsigned short*)(ws);
  unsigned short* H1   = (unsigned short*)(ws + XB);
  int*            nbrT = (int*)(ws + 2 * XB);
  size_t off = 2 * XB + (size_t)KOFF * NPTS * 4;
  unsigned short* WL1 = (unsigned short*)(ws + off); off += KOFF * 1024 * 2;
  unsigned short* WL2 = (unsigned short*)(ws + off); off += KOFF * 1024 * 2;
  float* stats1 = (float*)(ws + off); off += 256;
  float* stats2 = (float*)(ws + off); off += 256;
  unsigned short* H2 = Xb;   // overlay: Xb dead after conv1

  prep_all<<<6250, 256, 0, stream>>>(feats, Xb, H1, stats1, nbr, mask, nbrT, W1, W2, WL1, WL2);

  conv_mfma16<<<3125, 512, 0, stream>>>(Xb, nbrT, WL1, H1, stats1);
  bn_relu_fused<<<6250, 256, 0, stream>>>(H1, stats1, gamma1, beta1);

  conv_mfma16<<<3125, 512, 0, stream>>>(H1, nbrT, WL2, H2, stats2);
  bn_res_relu_out<<<6250, 256, 0, stream>>>(H2, feats, stats2, gamma2, beta2, (float*)d_out);
}

// Round 7
// 406.563 us; speedup vs baseline: 1.5082x; 1.4746x over previous
//
#include <hip/hip_runtime.h>

#define NPTS 400000
#define KOFF 27

typedef __attribute__((ext_vector_type(8))) __bf16 bf16x8;
typedef __attribute__((ext_vector_type(4))) float v4f;

__device__ __forceinline__ float bf2f(unsigned short u) {
  union { unsigned int i; float f; } v; v.i = ((unsigned int)u) << 16; return v.f;
}
__device__ __forceinline__ unsigned short f2bf(float f) {
  union { float f; unsigned int i; } v; v.f = f;
  unsigned int x = v.i;
  return (unsigned short)((x + 0x7FFFu + ((x >> 16) & 1u)) >> 16);  // RNE
}

// ---------------------------------------------------------------- fused prep:
//  all blocks: feats -> bf16 table;  block 0: sentinels + stats zero
//  blocks <1563: nbr/mask -> masked transposed nbrT (LDS tile)
//  blocks 1563..1670: W -> fragment-major bf16
__global__ void prep_all(const float* __restrict__ feats, unsigned short* __restrict__ Xb,
                         unsigned short* __restrict__ H1, float* __restrict__ statszero,
                         const int* __restrict__ nbr, const int* __restrict__ mask,
                         int* __restrict__ nbrT,
                         const float* __restrict__ W1, const float* __restrict__ W2,
                         unsigned short* __restrict__ WL1, unsigned short* __restrict__ WL2) {
  __shared__ int tile[256 * KOFF];
  int idx = blockIdx.x * 256 + threadIdx.x;          // 6250*256 = 1.6M = NPTS*32/8
  const float4* f4 = (const float4*)feats;
  float4 a = f4[2 * idx], b = f4[2 * idx + 1];
  union { unsigned short u[8]; uint4 v; } p;
  p.u[0] = f2bf(a.x); p.u[1] = f2bf(a.y); p.u[2] = f2bf(a.z); p.u[3] = f2bf(a.w);
  p.u[4] = f2bf(b.x); p.u[5] = f2bf(b.y); p.u[6] = f2bf(b.z); p.u[7] = f2bf(b.w);
  ((uint4*)Xb)[idx] = p.v;
  if (blockIdx.x == 0) {
    if (threadIdx.x < 32) {                           // zero sentinel row NPTS in both gatherable tables
      Xb[(size_t)NPTS * 32 + threadIdx.x] = 0;
      H1[(size_t)NPTS * 32 + threadIdx.x] = 0;
    }
    if (threadIdx.x < 128) statszero[threadIdx.x] = 0.f;  // stats1[64] + stats2[64] contiguous
  }
  if (blockIdx.x < 1563) {                            // nbr tile transpose
    int p0 = blockIdx.x * 256;
    int cnt = (NPTS - p0 < 256) ? (NPTS - p0) : 256;
    int total = cnt * KOFF;
    for (int i = threadIdx.x; i < total; i += 256) {
      int j = nbr[(size_t)p0 * KOFF + i];
      int mk = mask[(size_t)p0 * KOFF + i];
      tile[i] = (mk != 0) ? j : NPTS;                 // sentinel -> zero row
    }
    __syncthreads();
    int t = threadIdx.x;
    if (t < cnt) {
      #pragma unroll
      for (int k = 0; k < KOFF; ++k)
        nbrT[(size_t)k * NPTS + p0 + t] = tile[t * KOFF + k];
    }
  } else if (blockIdx.x < 1563 + 108) {               // W -> fragment-major
    int widx = (blockIdx.x - 1563) * 256 + threadIdx.x;
    if (widx < KOFF * 1024) {
      int k = widx >> 10, r = widx & 1023;
      int h = r >> 9, rr = r & 511;
      int lane = rr >> 3, j = rr & 7;
      int i_ch = (lane >> 4) * 8 + j;
      int o_ch = h * 16 + (lane & 15);
      int src = k * 1024 + i_ch * 32 + o_ch;
      WL1[widx] = f2bf(W1[src]);
      WL2[widx] = f2bf(W2[src]);
    }
  }
}

// ---------------------------------------------------------------- sparse conv, 16x16x32 MFMA
// R4 inner structure (compiler-scheduled deep pipeline, NO sched_barriers),
// at 1024-thr / 16-wave blocks: 54KB W-LDS -> 2 blocks/CU -> 32 waves/CU.
__global__ __launch_bounds__(1024, 8) void conv_mfma16(
    const unsigned short* __restrict__ X,     // (NPTS+1) x 32 bf16, row NPTS = zeros
    const int* __restrict__ nbrT,             // [27][NPTS]
    const unsigned short* __restrict__ WL,    // fragment-major [27][2][64][8] bf16
    unsigned short* __restrict__ Hout,        // [NPTS][32] bf16
    float* __restrict__ stats)                // [64]: sum, sumsq
{
  __shared__ unsigned char wlds[KOFF * 2048]; // 54 KB: [k][h][lane][16B]
  __shared__ float redS[16][32];
  __shared__ float redQ[16][32];

  const int tid  = threadIdx.x;
  const int lane = tid & 63;
  const int wv   = tid >> 6;            // 0..15
  const int m    = lane & 15;           // point-in-tile / out-ch
  const int q    = lane >> 4;           // input-channel chunk
  int n0 = blockIdx.x * 256 + wv * 16;  // 1563*256 = 400128: last block waves 8..15 inactive
  const bool active = (n0 < NPTS);      // NPTS % 16 == 0 -> all-or-nothing per wave
  if (!active) n0 = NPTS - 16;          // clamped duplicate work, stores/stats gated

  {// stage W fragments once per block (3456 uint4, 1024 threads)
    const uint4* src = (const uint4*)WL;
    uint4* dst = (uint4*)wlds;
    #pragma unroll
    for (int i = 0; i < 4; ++i) {
      int ii = i * 1024 + tid;
      if (ii < KOFF * 128) dst[ii] = src[ii];
    }
  }
  __syncthreads();

  // prefetch all 27 neighbor indices (independent, coalesced)
  const int* nbp = nbrT + n0 + m;
  int nb[KOFF];
  #pragma unroll
  for (int k = 0; k < KOFF; ++k) nb[k] = nbp[k * NPTS];

  const unsigned short* xq = X + q * 8;
  const bf16x8* wfrag = (const bf16x8*)wlds;

  v4f acc0 = {0.f, 0.f, 0.f, 0.f};
  v4f acc1 = {0.f, 0.f, 0.f, 0.f};

  bf16x8 A0[9], A1[9];
  #pragma unroll
  for (int k = 0; k < 9; ++k) A0[k] = *(const bf16x8*)(xq + (size_t)nb[k] * 32);
  #pragma unroll
  for (int k = 0; k < 9; ++k) A1[k] = *(const bf16x8*)(xq + (size_t)nb[9 + k] * 32);

  #pragma unroll
  for (int k = 0; k < 9; ++k) {        // chunk 1 compute
    bf16x8 b0 = wfrag[(k * 2 + 0) * 64 + lane];
    bf16x8 b1 = wfrag[(k * 2 + 1) * 64 + lane];
    acc0 = __builtin_amdgcn_mfma_f32_16x16x32_bf16(A0[k], b0, acc0, 0, 0, 0);
    acc1 = __builtin_amdgcn_mfma_f32_16x16x32_bf16(A0[k], b1, acc1, 0, 0, 0);
  }
  #pragma unroll
  for (int k = 0; k < 9; ++k) A0[k] = *(const bf16x8*)(xq + (size_t)nb[18 + k] * 32);  // chunk 3 gathers overlap chunk 2 MFMAs
  #pragma unroll
  for (int k = 0; k < 9; ++k) {        // chunk 2 compute
    int kk = 9 + k;
    bf16x8 b0 = wfrag[(kk * 2 + 0) * 64 + lane];
    bf16x8 b1 = wfrag[(kk * 2 + 1) * 64 + lane];
    acc0 = __builtin_amdgcn_mfma_f32_16x16x32_bf16(A1[k], b0, acc0, 0, 0, 0);
    acc1 = __builtin_amdgcn_mfma_f32_16x16x32_bf16(A1[k], b1, acc1, 0, 0, 0);
  }
  #pragma unroll
  for (int k = 0; k < 9; ++k) {        // chunk 3 compute
    int kk = 18 + k;
    bf16x8 b0 = wfrag[(kk * 2 + 0) * 64 + lane];
    bf16x8 b1 = wfrag[(kk * 2 + 1) * 64 + lane];
    acc0 = __builtin_amdgcn_mfma_f32_16x16x32_bf16(A0[k], b0, acc0, 0, 0, 0);
    acc1 = __builtin_amdgcn_mfma_f32_16x16x32_bf16(A0[k], b1, acc1, 0, 0, 0);
  }

  // epilogue: C/D layout col=lane&15 (=out ch m), row=(lane>>4)*4+r (=point)
  float s0 = 0.f, s1 = 0.f, qq0 = 0.f, qq1 = 0.f;
  if (active) {
    #pragma unroll
    for (int r = 0; r < 4; ++r) {
      float v0 = acc0[r], v1 = acc1[r];
      s0 += v0; s1 += v1; qq0 += v0 * v0; qq1 += v1 * v1;
      size_t pt = (size_t)(n0 + q * 4 + r);
      Hout[pt * 32 + m]      = f2bf(v0);
      Hout[pt * 32 + 16 + m] = f2bf(v1);
    }
  }
  // BN stats: reduce over point-chunk lanes (bits 4,5)
  s0  += __shfl_xor(s0, 16);  s0  += __shfl_xor(s0, 32);
  s1  += __shfl_xor(s1, 16);  s1  += __shfl_xor(s1, 32);
  qq0 += __shfl_xor(qq0, 16); qq0 += __shfl_xor(qq0, 32);
  qq1 += __shfl_xor(qq1, 16); qq1 += __shfl_xor(qq1, 32);
  if (lane < 16) {
    redS[wv][m] = s0; redS[wv][m + 16] = s1;
    redQ[wv][m] = qq0; redQ[wv][m + 16] = qq1;
  }
  __syncthreads();
  if (tid < 64) {
    int t = tid & 31;
    float a = 0.f;
    if (tid < 32) { for (int w = 0; w < 16; ++w) a += redS[w][t]; }
    else          { for (int w = 0; w < 16; ++w) a += redQ[w][t]; }
    atomicAdd(&stats[tid], a);
  }
}

// ---------------------------------------------------------------- BN(+finalize) + ReLU in place (bf16)
__global__ void bn_relu_fused(unsigned short* __restrict__ H, const float* __restrict__ stats,
                              const float* __restrict__ gamma, const float* __restrict__ beta) {
  __shared__ float sb[64];
  if (threadIdx.x < 32) {
    int t = threadIdx.x;
    float mean = stats[t] * (1.f / NPTS);
    float var  = stats[t + 32] * (1.f / NPTS) - mean * mean;
    float rstd = rsqrtf(var + 1e-5f);
    float sc = gamma[t] * rstd;
    sb[t] = sc; sb[t + 32] = beta[t] - mean * sc;
  }
  __syncthreads();
  int idx = blockIdx.x * 256 + threadIdx.x;          // 1.6M
  uint4 v = ((uint4*)H)[idx];
  union { uint4 v; unsigned short u[8]; } p; p.v = v;
  int baseo = (idx * 8) & 31;
  #pragma unroll
  for (int j = 0; j < 8; ++j) {
    float f = bf2f(p.u[j]);
    f = fmaxf(f * sb[baseo + j] + sb[32 + baseo + j], 0.f);
    p.u[j] = f2bf(f);
  }
  ((uint4*)H)[idx] = p.v;
}

// ---------------------------------------------------------------- BN(+finalize) + residual + ReLU -> fp32 out
__global__ void bn_res_relu_out(const unsigned short* __restrict__ H2, const float* __restrict__ feats,
                                const float* __restrict__ stats, const float* __restrict__ gamma,
                                const float* __restrict__ beta, float* __restrict__ out) {
  __shared__ float sb[64];
  if (threadIdx.x < 32) {
    int t = threadIdx.x;
    float mean = stats[t] * (1.f / NPTS);
    float var  = stats[t + 32] * (1.f / NPTS) - mean * mean;
    float rstd = rsqrtf(var + 1e-5f);
    float sc = gamma[t] * rstd;
    sb[t] = sc; sb[t + 32] = beta[t] - mean * sc;
  }
  __syncthreads();
  int idx = blockIdx.x * 256 + threadIdx.x;          // 1.6M
  uint4 v = ((const uint4*)H2)[idx];
  union { uint4 v; unsigned short u[8]; } p; p.v = v;
  int baseo = (idx * 8) & 31;
  const float4* f4 = (const float4*)feats;
  float4 fa = f4[2 * idx], fb = f4[2 * idx + 1];
  float4 o0, o1;
  float* fav = (float*)&fa; float* fbv = (float*)&fb;
  float* o0v = (float*)&o0; float* o1v = (float*)&o1;
  #pragma unroll
  for (int j = 0; j < 4; ++j)
    o0v[j] = fmaxf(bf2f(p.u[j]) * sb[baseo + j] + sb[32 + baseo + j] + fav[j], 0.f);
  #pragma unroll
  for (int j = 0; j < 4; ++j)
    o1v[j] = fmaxf(bf2f(p.u[4 + j]) * sb[baseo + 4 + j] + sb[32 + baseo + 4 + j] + fbv[j], 0.f);
  ((float4*)out)[2 * idx] = o0;
  ((float4*)out)[2 * idx + 1] = o1;
}

// ----------------------------------------------------------------
extern "C" void kernel_launch(void* const* d_in, const int* in_sizes, int n_in,
                              void* d_out, int out_size, void* d_ws, size_t ws_size,
                              hipStream_t stream) {
  const float* feats  = (const float*)d_in[0];
  const float* W1     = (const float*)d_in[1];
  const float* gamma1 = (const float*)d_in[2];
  const float* beta1  = (const float*)d_in[3];
  const float* W2     = (const float*)d_in[4];
  const float* gamma2 = (const float*)d_in[5];
  const float* beta2  = (const float*)d_in[6];
  const int*   nbr    = (const int*)d_in[7];
  const int*   mask   = (const int*)d_in[8];   // jnp bool uploaded as int32

  char* ws = (char*)d_ws;
  const size_t XB = ((size_t)(NPTS + 1) * 32 * 2 + 255) & ~(size_t)255;
  unsigned short* Xb   = (unsigned short*)(ws);
  unsigned short* H1   = (unsigned short*)(ws + XB);
  int*            nbrT = (int*)(ws + 2 * XB);
  size_t off = 2 * XB + (size_t)KOFF * NPTS * 4;
  unsigned short* WL1 = (unsigned short*)(ws + off); off += KOFF * 1024 * 2;
  unsigned short* WL2 = (unsigned short*)(ws + off); off += KOFF * 1024 * 2;
  float* stats1 = (float*)(ws + off); off += 256;
  float* stats2 = (float*)(ws + off); off += 256;
  unsigned short* H2 = Xb;   // overlay: Xb dead after conv1

  prep_all<<<6250, 256, 0, stream>>>(feats, Xb, H1, stats1, nbr, mask, nbrT, W1, W2, WL1, WL2);

  conv_mfma16<<<1563, 1024, 0, stream>>>(Xb, nbrT, WL1, H1, stats1);
  bn_relu_fused<<<6250, 256, 0, stream>>>(H1, stats1, gamma1, beta1);

  conv_mfma16<<<1563, 1024, 0, stream>>>(H1, nbrT, WL2, H2, stats2);
  bn_res_relu_out<<<6250, 256, 0, stream>>>(H2, feats, stats2, gamma2, beta2, (float*)d_out);
}